// Round 7
// baseline (172.886 us; speedup 1.0000x reference)
//
#include <hip/hip_runtime.h>
#include <cstdint>

namespace {
constexpr int NWIN = 4096;
constexpr int NT   = 49;
constexpr int D    = 128;
constexpr float SCALE = 0.17677669529663687f;  // 1/sqrt(32)

constexpr int SQ = 136;   // row stride (ushorts) for token-major Q/K/attn-out
constexpr int SV = 72;    // row stride for V^T

// wbuf layout (ushort element offsets)
constexpr size_t WQH   = 0;       // qkv_w hi frags (Q cols pre-scaled): 24nt*4ks*64*8 = 49152
constexpr size_t WOH   = 49152;   // wo_w hi frags: 8nt*4ks*64*8 = 16384
constexpr size_t WOL   = 65536;   // wo_w lo frags: 16384
constexpr size_t BFRAG = 81920;   // bias frags: 16 pairs * 64 lanes * 16 = 16384
constexpr size_t WBUF_BYTES = 98304 * 2;
}

using short8 = __attribute__((ext_vector_type(8))) short;
using f32x4  = __attribute__((ext_vector_type(4))) float;

__device__ __forceinline__ ushort f2bf(float x) {           // round-to-nearest-even
    uint u = __builtin_bit_cast(uint, x);
    uint r = u + 0x7FFFu + ((u >> 16) & 1u);
    return (ushort)(r >> 16);
}
__device__ __forceinline__ float bf2f(ushort b) {
    uint u = ((uint)b) << 16;
    return __builtin_bit_cast(float, u);
}
__device__ __forceinline__ uint pack_bf2(float a, float b) {
    return ((uint)f2bf(a)) | (((uint)f2bf(b)) << 16);
}
#define SBAR() __builtin_amdgcn_sched_barrier(0)

// Prep: qkv hi frags (Q pre-scaled), wo hi+lo frags, bias frags.
__global__ __launch_bounds__(256) void prep_all(
    const float* __restrict__ qkv_w, const float* __restrict__ wo_w,
    const float* __restrict__ bias_table, const int* __restrict__ bias_index,
    ushort* __restrict__ wbuf)
{
    const int blk = blockIdx.x, tid = threadIdx.x;
    if (blk < 96) {
        const int nt = blk >> 2, ks = blk & 3;
        for (int e = tid; e < 512; e += 256) {
            const int lane = e >> 3, j = e & 7;
            const int k = ks * 32 + (lane >> 4) * 8 + j;
            const int n = nt * 16 + (lane & 15);
            float wv = qkv_w[(size_t)k * 384 + n];
            if (n < 128) wv *= SCALE;   // fold attention scale into Q columns
            wbuf[WQH + ((size_t)(nt * 4 + ks) * 64 + lane) * 8 + j] = f2bf(wv);
        }
    } else if (blk < 128) {
        const int b2 = blk - 96;
        const int nt = b2 >> 2, ks = b2 & 3;
        for (int e = tid; e < 512; e += 256) {
            const int lane = e >> 3, j = e & 7;
            const int k = ks * 32 + (lane >> 4) * 8 + j;
            const int n = nt * 16 + (lane & 15);
            const float wv = wo_w[(size_t)k * 128 + n];
            const ushort h = f2bf(wv);
            const size_t fo = ((size_t)(nt * 4 + ks) * 64 + lane) * 8 + j;
            wbuf[WOH + fo] = h;
            wbuf[WOL + fo] = f2bf(wv - bf2f(h));
        }
    } else {
        // bias frag for pair p: h = p>>2, qt = p&3.
        // element ei = lane*16 + t*4 + r -> q = qt*16+(lane&15), k = 16t+4*(lane>>4)+r
        const int p = blk - 128;
        const int h = p >> 2, qt = p & 3;
        for (int ei = tid; ei < 1024; ei += 256) {
            const int lane = ei >> 4, t = (ei >> 2) & 3, r = ei & 3;
            const int q = qt * 16 + (lane & 15);
            const int k = 16 * t + 4 * (lane >> 4) + r;
            float v = 0.f;
            if (q < NT && k < NT) v = bias_table[bias_index[q * NT + k] * 4 + h];
            wbuf[BFRAG + (size_t)p * 1024 + ei] = f2bf(v);
        }
    }
}

// LDS map (53248 B):
//   [0,      8704)  s_qh : Q (ph2-3), then attn-out (ph3-4)   [64][136]
//   [8704,  17408)  s_kh : K                                  [64][136]
//   [17408, 26624)  s_vt : V^T, sigma-permuted columns        [128][72]
template <bool PREPPED>
__global__ __launch_bounds__(512, 4) void win_attn(
    const float* __restrict__ x,
    const float* __restrict__ qkv_w, const float* __restrict__ qkv_b,
    const float* __restrict__ wo_w,  const float* __restrict__ wo_b,
    const float* __restrict__ bias_table, const int* __restrict__ bias_index,
    const ushort* __restrict__ wbuf, float* __restrict__ out)
{
    __shared__ __align__(16) ushort s_all[26624];
    ushort* const s_qh = s_all;
    ushort* const s_kh = s_all + 8704;
    ushort* const s_vt = s_all + 17408;

    const int b = blockIdx.x, tid = threadIdx.x;
    const int wid = tid >> 6, lane = tid & 63;
    const int g = lane >> 4, lr = lane & 15;
    const int m = wid >> 1;            // token quarter owned in GEMM phases
    const int nt0 = (wid & 1) * 12;    // qkv n-tile base
    const float* xb = x + (size_t)b * NT * D;

    auto loadQB = [&](int nt, int ks) -> short8 {
        if constexpr (PREPPED) {
            return *reinterpret_cast<const short8*>(
                &wbuf[WQH + ((size_t)(nt * 4 + ks) * 64 + lane) * 8]);
        } else {
            short8 r;
            #pragma unroll
            for (int j = 0; j < 8; ++j) {
                float wv = qkv_w[(size_t)(ks * 32 + g * 8 + j) * 384 + nt * 16 + lr];
                if (nt < 8) wv *= SCALE;
                r[j] = (short)f2bf(wv);
            }
            return r;
        }
    };
    auto loadWO = [&](int nt, int ks, short8& h8, short8& l8) {
        if constexpr (PREPPED) {
            const size_t fo = ((size_t)(nt * 4 + ks) * 64 + lane) * 8;
            h8 = *reinterpret_cast<const short8*>(&wbuf[WOH + fo]);
            l8 = *reinterpret_cast<const short8*>(&wbuf[WOL + fo]);
        } else {
            #pragma unroll
            for (int j = 0; j < 8; ++j) {
                const float wv = wo_w[(size_t)(ks * 32 + g * 8 + j) * 128 + nt * 16 + lr];
                const ushort hh = f2bf(wv);
                h8[j] = (short)hh;
                l8[j] = (short)f2bf(wv - bf2f(hh));
            }
        }
    };

    // ---- Phase 0: x A-frags straight into registers (row 16m+lr, 4 ks) ----
    short8 Ax[4];
    {
        const int row = m * 16 + lr;
        if (row < NT) {
            const float* xr = xb + row * D;
            #pragma unroll
            for (int ks = 0; ks < 4; ++ks) {
                const float4 v0 = *reinterpret_cast<const float4*>(&xr[ks * 32 + g * 8]);
                const float4 v1 = *reinterpret_cast<const float4*>(&xr[ks * 32 + g * 8 + 4]);
                uint4 w;
                w.x = pack_bf2(v0.x, v0.y); w.y = pack_bf2(v0.z, v0.w);
                w.z = pack_bf2(v1.x, v1.y); w.w = pack_bf2(v1.z, v1.w);
                Ax[ks] = __builtin_bit_cast(short8, w);
            }
        } else {
            #pragma unroll
            for (int ks = 0; ks < 4; ++ks) Ax[ks] = short8{0,0,0,0,0,0,0,0};
        }
    }
    // qkv bias values for this wave's 12 n-tiles
    float qb[12];
    #pragma unroll
    for (int i = 0; i < 12; ++i) {
        const int nt = nt0 + i;
        float v = qkv_b[nt * 16 + lr];
        if (nt < 8) v *= SCALE;
        qb[i] = v;
    }

    uint bw[2][8];   // phase-3 bias fragments (prefetched in phase-2 tail)

    // ---- Phase 2: QKV = x @ qkv_w + qkv_b; explicit 12-deep B pipeline ----
    {
        short8 Bf[12];
        f32x4 acc[6];
        // preload pass0 ks=0,1
        #pragma unroll
        for (int i = 0; i < 6; ++i) Bf[i] = loadQB(nt0 + i, 0);
        #pragma unroll
        for (int i = 0; i < 6; ++i) Bf[6 + i] = loadQB(nt0 + i, 1);
        SBAR();
        #pragma unroll
        for (int pass = 0; pass < 2; ++pass) {
            const int ntb = nt0 + pass * 6;
            #pragma unroll
            for (int i = 0; i < 6; ++i) acc[i] = f32x4{0.f, 0.f, 0.f, 0.f};
            #pragma unroll
            for (int ks = 0; ks < 4; ++ks) {
                __builtin_amdgcn_s_setprio(1);
                #pragma unroll
                for (int i = 0; i < 6; ++i)
                    acc[i] = __builtin_amdgcn_mfma_f32_16x16x32_bf16(Ax[ks], Bf[(ks & 1) * 6 + i], acc[i], 0, 0, 0);
                __builtin_amdgcn_s_setprio(0);
                SBAR();
                if (ks < 2) {   // prefetch ks+2 into the buffer just freed
                    #pragma unroll
                    for (int i = 0; i < 6; ++i) Bf[(ks & 1) * 6 + i] = loadQB(ntb + i, ks + 2);
                    SBAR();
                }
            }
            if (pass == 0) {
                // preload pass1 ks=0,1 (hidden under pass0 epilogue)
                #pragma unroll
                for (int i = 0; i < 6; ++i) Bf[i] = loadQB(nt0 + 6 + i, 0);
                #pragma unroll
                for (int i = 0; i < 6; ++i) Bf[6 + i] = loadQB(nt0 + 6 + i, 1);
                SBAR();
            } else {
                // prefetch phase-3 bias fragments (hidden under pass1 epilogue)
                #pragma unroll
                for (int pi = 0; pi < 2; ++pi) {
                    const int p = wid * 2 + pi;
                    if constexpr (PREPPED) {
                        const uint4 b0 = *reinterpret_cast<const uint4*>(&wbuf[BFRAG + ((size_t)p * 64 + lane) * 16]);
                        const uint4 b1 = *reinterpret_cast<const uint4*>(&wbuf[BFRAG + ((size_t)p * 64 + lane) * 16 + 8]);
                        bw[pi][0] = b0.x; bw[pi][1] = b0.y; bw[pi][2] = b0.z; bw[pi][3] = b0.w;
                        bw[pi][4] = b1.x; bw[pi][5] = b1.y; bw[pi][6] = b1.z; bw[pi][7] = b1.w;
                    } else {
                        const int h = p >> 2, qt = p & 3;
                        const int q = qt * 16 + lr;
                        #pragma unroll
                        for (int t = 0; t < 4; ++t) {
                            #pragma unroll
                            for (int r = 0; r < 4; r += 2) {
                                const int k0 = 16 * t + 4 * g + r, k1 = k0 + 1;
                                float v0 = 0.f, v1 = 0.f;
                                if (q < NT && k0 < NT) v0 = bias_table[bias_index[q * NT + k0] * 4 + h];
                                if (q < NT && k1 < NT) v1 = bias_table[bias_index[q * NT + k1] * 4 + h];
                                bw[pi][(4 * t + r) >> 1] = ((uint)f2bf(v0)) | (((uint)f2bf(v1)) << 16);
                            }
                        }
                    }
                }
                SBAR();
            }
            // Epilogue: Q (scaled, trunc), K (trunc) token-major; V^T sigma-permuted (RNE).
            #pragma unroll
            for (int i = 0; i < 6; ++i) {
                const int nt = ntb + i;
                const int n = nt * 16 + lr;
                const float bias = qb[pass * 6 + i];
                if (nt < 16) {
                    ushort* const dst = (nt < 8) ? s_qh : s_kh;
                    const int col = n & 127;
                    #pragma unroll
                    for (int jj = 0; jj < 4; ++jj) {
                        const int q = m * 16 + g * 4 + jj;
                        dst[q * SQ + col] = (ushort)(__builtin_bit_cast(uint, acc[i][jj] + bias) >> 16);
                    }
                } else {
                    const int d = n - 256;
                    // q = 16m + 4g + jj -> col cbase + jj (sigma permutation)
                    const int cbase = 32 * (m >> 1) + 8 * ((4 * m + g) & 3) + 4 * (m & 1);
                    ushort4 hv;
                    #pragma unroll
                    for (int jj = 0; jj < 4; ++jj)
                        (&hv.x)[jj] = f2bf(acc[i][jj] + bias);   // RNE (un-damped path)
                    *reinterpret_cast<ushort4*>(&s_vt[d * SV + cbase]) = hv;
                }
            }
        }
    }
    __syncthreads();   // B: Q/K/V ready

    short8 Wh[2][4], Wl[2][4];
    float wb4[4];

    // ---- Phase 3: wave-local attention; wave owns pairs p = 2wid, 2wid+1 ----
    // scores: mfma(K,Q) -> lane (g,lr): P[q=qt*16+lr][k=16t+4g+r]
    // PV A-frag(ks) slot (g,j) relabeled to token sigma = 32ks+16*(j>>2)+4g+(j&3),
    // matching the sigma-permuted V^T columns.
    {
        short8 pa[2][2];
        float inv2[2];
        #pragma unroll
        for (int pi = 0; pi < 2; ++pi) {
            const int p = wid * 2 + pi;
            const int h = p >> 2, qt = p & 3;
            const short8 Qf = *reinterpret_cast<const short8*>(&s_qh[(qt * 16 + lr) * SQ + h * 32 + g * 8]);
            f32x4 sc[4];
            __builtin_amdgcn_s_setprio(1);
            #pragma unroll
            for (int t = 0; t < 4; ++t) {
                const short8 Kf = *reinterpret_cast<const short8*>(&s_kh[(t * 16 + lr) * SQ + h * 32 + g * 8]);
                f32x4 z = {};
                sc[t] = __builtin_amdgcn_mfma_f32_16x16x32_bf16(Kf, Qf, z, 0, 0, 0);
            }
            __builtin_amdgcn_s_setprio(0);
            // exp, truncate to bf16, sum truncated values (trunc bias cancels in normalize)
            float lsum = 0.f;
            uint pw[8];
            #pragma unroll
            for (int t = 0; t < 4; ++t) {
                float ebits[4];
                #pragma unroll
                for (int r = 0; r < 4; ++r) {
                    const int idx = 4 * t + r;
                    const uint bwv = bw[pi][idx >> 1];
                    const float bv = __builtin_bit_cast(float, (idx & 1) ? (bwv & 0xFFFF0000u) : (bwv << 16));
                    float e;
                    if (t < 3) {
                        e = __expf(sc[t][r] + bv);
                    } else if (r == 0) {
                        e = (g == 0) ? __expf(sc[t][0] + bv) : 0.f;   // k = 48 valid only at g==0
                    } else {
                        e = 0.f;
                    }
                    const uint tr = __builtin_bit_cast(uint, e) & 0xFFFF0000u;
                    ebits[r] = __builtin_bit_cast(float, tr);
                    lsum += ebits[r];
                }
                pw[t * 2 + 0] = (__builtin_bit_cast(uint, ebits[0]) >> 16) | (__builtin_bit_cast(uint, ebits[1]) & 0xFFFF0000u);
                pw[t * 2 + 1] = (__builtin_bit_cast(uint, ebits[2]) >> 16) | (__builtin_bit_cast(uint, ebits[3]) & 0xFFFF0000u);
            }
            lsum += __shfl_xor(lsum, 16);
            lsum += __shfl_xor(lsum, 32);
            inv2[pi] = 1.f / lsum;
            #pragma unroll
            for (int ks = 0; ks < 2; ++ks) {
                uint4 w;
                w.x = pw[(2 * ks) * 2 + 0]; w.y = pw[(2 * ks) * 2 + 1];
                w.z = pw[(2 * ks + 1) * 2 + 0]; w.w = pw[(2 * ks + 1) * 2 + 1];
                pa[pi][ks] = __builtin_bit_cast(short8, w);
            }
        }

        // PV: O[q][d] for own pairs; D row = 4g+reg -> q, col lr -> d
        f32x4 oac[2][2];
        __builtin_amdgcn_s_setprio(1);
        #pragma unroll
        for (int pi = 0; pi < 2; ++pi) {
            const int p = wid * 2 + pi;
            const int h = p >> 2;
            #pragma unroll
            for (int dt = 0; dt < 2; ++dt) {
                f32x4 o = {};
                #pragma unroll
                for (int ks = 0; ks < 2; ++ks) {
                    const short8 Vf = *reinterpret_cast<const short8*>(&s_vt[(h * 32 + dt * 16 + lr) * SV + ks * 32 + g * 8]);
                    o = __builtin_amdgcn_mfma_f32_16x16x32_bf16(pa[pi][ks], Vf, o, 0, 0, 0);
                }
                oac[pi][dt] = o;
            }
        }
        __builtin_amdgcn_s_setprio(0);
        SBAR();
        // prefetch phase-4 ks=0 weight frags + wo bias (no LDS dependency)
        {
            const int nt04 = (wid & 1) * 4;
            #pragma unroll
            for (int i = 0; i < 4; ++i) loadWO(nt04 + i, 0, Wh[0][i], Wl[0][i]);
            #pragma unroll
            for (int i = 0; i < 4; ++i) wb4[i] = wo_b[(nt04 + i) * 16 + lr];
        }
        SBAR();
        __syncthreads();   // C: all Q/K/V reads done -> attn-out may overwrite Q
        // prefetch phase-4 ks=1 (hidden under attn-out epilogue + barrier D)
        {
            const int nt04 = (wid & 1) * 4;
            #pragma unroll
            for (int i = 0; i < 4; ++i) loadWO(nt04 + i, 1, Wh[1][i], Wl[1][i]);
        }
        SBAR();

        #pragma unroll
        for (int pi = 0; pi < 2; ++pi) {
            const int p = wid * 2 + pi;
            const int h = p >> 2, qt = p & 3;
            #pragma unroll
            for (int dt = 0; dt < 2; ++dt) {
                const int d = h * 32 + dt * 16 + lr;
                #pragma unroll
                for (int r = 0; r < 4; ++r) {
                    const float inv = __shfl(inv2[pi], 4 * g + r);
                    const int q = qt * 16 + 4 * g + r;
                    s_qh[q * SQ + d] = f2bf(oac[pi][dt][r] * inv);   // RNE
                }
            }
        }
    }
    __syncthreads();   // D: attn-out ready

    // ---- Phase 4: out = attn @ wo_w + wo_b (attn hi x wo hi+lo, 2-deep pipeline) ----
    {
        const int nt04 = (wid & 1) * 4;
        short8 Ah4[4];
        #pragma unroll
        for (int ks = 0; ks < 4; ++ks)
            Ah4[ks] = *reinterpret_cast<const short8*>(&s_qh[(m * 16 + lr) * SQ + ks * 32 + g * 8]);
        f32x4 acc[4] = {};
        #pragma unroll
        for (int ks = 0; ks < 4; ++ks) {
            __builtin_amdgcn_s_setprio(1);
            #pragma unroll
            for (int i = 0; i < 4; ++i) {
                acc[i] = __builtin_amdgcn_mfma_f32_16x16x32_bf16(Ah4[ks], Wh[ks & 1][i], acc[i], 0, 0, 0);
                acc[i] = __builtin_amdgcn_mfma_f32_16x16x32_bf16(Ah4[ks], Wl[ks & 1][i], acc[i], 0, 0, 0);
            }
            __builtin_amdgcn_s_setprio(0);
            SBAR();
            if (ks < 2) {
                #pragma unroll
                for (int i = 0; i < 4; ++i) loadWO(nt04 + i, ks + 2, Wh[ks & 1][i], Wl[ks & 1][i]);
                SBAR();
            }
        }
        float* ob = out + (size_t)b * NT * D;
        #pragma unroll
        for (int i = 0; i < 4; ++i) {
            const int n = (nt04 + i) * 16 + lr;
            #pragma unroll
            for (int jj = 0; jj < 4; ++jj) {
                const int q = m * 16 + g * 4 + jj;
                if (q < NT) ob[q * D + n] = acc[i][jj] + wb4[i];
            }
        }
    }
}

extern "C" void kernel_launch(void* const* d_in, const int* in_sizes, int n_in,
                              void* d_out, int out_size, void* d_ws, size_t ws_size,
                              hipStream_t stream) {
    const float* x          = (const float*)d_in[0];
    const float* qkv_w      = (const float*)d_in[1];
    const float* qkv_b      = (const float*)d_in[2];
    const float* wo_w       = (const float*)d_in[3];
    const float* wo_b       = (const float*)d_in[4];
    const float* bias_table = (const float*)d_in[5];
    const int*   bias_index = (const int*)d_in[6];
    float* outp = (float*)d_out;

    if (ws_size >= WBUF_BYTES) {
        ushort* wbuf = (ushort*)d_ws;
        prep_all<<<dim3(144), dim3(256), 0, stream>>>(qkv_w, wo_w, bias_table, bias_index, wbuf);
        win_attn<true><<<dim3(NWIN), dim3(512), 0, stream>>>(
            x, qkv_w, qkv_b, wo_w, wo_b, bias_table, bias_index, wbuf, outp);
    } else {
        win_attn<false><<<dim3(NWIN), dim3(512), 0, stream>>>(
            x, qkv_w, qkv_b, wo_w, wo_b, bias_table, bias_index, nullptr, outp);
    }
}